// Round 1
// baseline (258.111 us; speedup 1.0000x reference)
//
#include <hip/hip_runtime.h>

// Masked dual-table embedding gather.
//   out[t, :] = (oov_map[x[t]] >= 0) ? oov_embed[oov_map[x[t]], :] : w2v[x[t], :]
// DIM = 300 floats = 75 float4 per row.
//
// 4 independent streams per thread (idx, idx+q, idx+2q, idx+3q with
// q = total_vec/4): 64 B in flight per lane, half the waves of the 2-stream
// version. Because n_tokens % 4 == 0, q is an exact multiple of VEC4, so all
// four streams share one idx/75 division: token_s = tok0 + s*(n_tokens/4),
// off_s = off. The compiler batches the 4 x-loads, 4 map-loads and 4 row-loads
// into three wide latency round-trips per 8 KB of wave traffic.
// NT stores keep the write stream out of L2/L3 so the 126 MB table set stays
// cache-resident for re-read rows.

#define DIM   300
#define VEC4  (DIM / 4)   // 75 float4 per row

typedef float v4 __attribute__((ext_vector_type(4)));

template <int S>
__global__ __launch_bounds__(256) void iov_gather_kernel(
    const int* __restrict__ x,        // [n_tokens]
    const v4*  __restrict__ w2v,      // [VOCAB * VEC4]
    const v4*  __restrict__ oov,      // [N_OOV * VEC4]
    const int* __restrict__ oov_map,  // [VOCAB]
    v4*        __restrict__ out,      // [n_tokens * VEC4]
    int chunk,                        // total_vec / S  (multiple of VEC4)
    int tok_chunk)                    // n_tokens / S
{
    int t = blockIdx.x * blockDim.x + threadIdx.x;
    if (t >= chunk) return;

    int tok0 = t / VEC4;              // single magic-multiply divide
    int off  = t - tok0 * VEC4;

    // Phase 1: S independent token-id loads (1-2 cache lines per wave each).
    int xid[S];
#pragma unroll
    for (int s = 0; s < S; ++s) xid[s] = x[tok0 + s * tok_chunk];

    // Phase 2: S independent map loads.
    int row[S];
#pragma unroll
    for (int s = 0; s < S; ++s) row[s] = oov_map[xid[s]];

    // Phase 3: S independent row-fragment loads (fully coalesced, 1 KB/wave each).
    v4 val[S];
#pragma unroll
    for (int s = 0; s < S; ++s) {
        const v4* src = (row[s] >= 0)
            ? (oov + (long long)row[s] * VEC4)
            : (w2v + (long long)xid[s] * VEC4);
        val[s] = src[off];
    }

#pragma unroll
    for (int s = 0; s < S; ++s)
        __builtin_nontemporal_store(val[s], out + t + s * chunk);
}

extern "C" void kernel_launch(void* const* d_in, const int* in_sizes, int n_in,
                              void* d_out, int out_size, void* d_ws, size_t ws_size,
                              hipStream_t stream) {
    const int* x       = (const int*)d_in[0];   // [B*S]
    const v4*  w2v     = (const v4*) d_in[1];   // [VOCAB, DIM]
    const v4*  oov     = (const v4*) d_in[2];   // [N_OOV, DIM]
    const int* oov_map = (const int*)d_in[3];   // [VOCAB]
    v4*        out     = (v4*)       d_out;

    const int n_tokens  = in_sizes[0];          // 131072
    const int total_vec = n_tokens * VEC4;      // 9,830,400

    const int block = 256;
    if (n_tokens % 4 == 0) {
        const int chunk = total_vec / 4;        // 2,457,600 (= 9600 * 256 exactly)
        const int grid  = (chunk + block - 1) / block;
        iov_gather_kernel<4><<<grid, block, 0, stream>>>(
            x, w2v, oov, oov_map, out, chunk, n_tokens / 4);
    } else if (n_tokens % 2 == 0) {
        const int chunk = total_vec / 2;
        const int grid  = (chunk + block - 1) / block;
        iov_gather_kernel<2><<<grid, block, 0, stream>>>(
            x, w2v, oov, oov_map, out, chunk, n_tokens / 2);
    } else {
        const int grid = (total_vec + block - 1) / block;
        iov_gather_kernel<1><<<grid, block, 0, stream>>>(
            x, w2v, oov, oov_map, out, total_vec, n_tokens);
    }
}